// Round 10
// baseline (130.342 us; speedup 1.0000x reference)
//
#include <hip/hip_runtime.h>

#define NSENT 64
#define NCAND 8192
#define LMAX  512
#define KOUT  128
#define TPB   512
#define CHUNK 1024
#define NCHUNK (NCAND / CHUNK)   // 8

#if defined(__has_builtin)
#if __has_builtin(__builtin_amdgcn_readlane)
#define READLANE(v, l) __builtin_amdgcn_readlane((unsigned)(v), (unsigned)(l))
#endif
#endif
#ifndef READLANE
#define READLANE(v, l) ((unsigned)__shfl((int)(v), (int)(l)))
#endif

// ---------------------------------------------------------------------------
// Kernel A: 512 blocks (sentence = bid>>3, chunk = bid&7). Hybrid bitonic
// sort of 1024 u64: thread t holds elements {t, t+512} in registers.
//   j<=32  : __shfl_xor exchange (no LDS, no barrier) - 45 stages
//   j=64..256: double-buffered LDS exchange (1 barrier each) - 9 stages
//   j=512  : in-register compare of (a,b) - 1 stage
// Key: high 32 = descending-orderable score bits, low 31 = (idx<<18)|(st<<9)|en
// ---------------------------------------------------------------------------
__global__ __launch_bounds__(TPB) void sort_chunks_kernel(
    const float* __restrict__ scores,
    const int*   __restrict__ starts,
    const int*   __restrict__ ends,
    unsigned long long* __restrict__ ws)
{
    __shared__ unsigned long long lb[2][CHUNK];   // 16 KiB double buffer
    const int  bid   = blockIdx.x;
    const int  sent  = bid >> 3;
    const int  chunk = bid & 7;
    const int  t     = threadIdx.x;
    const long gbase = (long)sent * NCAND + (long)chunk * CHUNK;

    unsigned long long a, b;
    {
        unsigned u0 = __float_as_uint(scores[gbase + t]);
        unsigned u1 = __float_as_uint(scores[gbase + t + 512]);
        unsigned o0 = (u0 & 0x80000000u) ? ~u0 : (u0 | 0x80000000u);
        unsigned o1 = (u1 & 0x80000000u) ? ~u1 : (u1 | 0x80000000u);
        unsigned st0 = (unsigned)starts[gbase + t];
        unsigned st1 = (unsigned)starts[gbase + t + 512];
        unsigned en0 = (unsigned)ends[gbase + t];
        unsigned en1 = (unsigned)ends[gbase + t + 512];
        unsigned g0 = (unsigned)(chunk * CHUNK + t);
        unsigned g1 = (unsigned)(chunk * CHUNK + t + 512);
        a = ((unsigned long long)(~o0) << 32) | (g0 << 18) | (st0 << 9) | en0;
        b = ((unsigned long long)(~o1) << 32) | (g1 << 18) | (st1 << 9) | en1;
    }

    int cur = 0;
    for (int k = 2; k <= CHUNK; k <<= 1) {
        for (int j = k >> 1; j > 0; j >>= 1) {
            const bool upa = ((t & k) == 0);
            const bool upb = (((t + 512) & k) == 0);
            if (j == 512) {                       // k==1024: pair (t, t+512) in-thread, up
                unsigned long long lo = (a < b) ? a : b;
                unsigned long long hi = (a < b) ? b : a;
                a = lo; b = hi;
            } else if (j >= 64) {                 // cross-wave: LDS exchange
                lb[cur][t] = a; lb[cur][t + 512] = b;
                __syncthreads();
                const unsigned long long pa = lb[cur][t ^ j];
                const unsigned long long pb = lb[cur][(t ^ j) + 512];
                cur ^= 1;
                const bool low = ((t & j) == 0);  // same for both elems (j<512)
                a = ((low == upa) == (a < pa)) ? a : pa;
                b = ((low == upb) == (b < pb)) ? b : pb;
            } else {                              // j<=32: same-wave shfl
                const unsigned long long pa = __shfl_xor(a, j);
                const unsigned long long pb = __shfl_xor(b, j);
                const bool low = ((t & j) == 0);
                a = ((low == upa) == (a < pa)) ? a : pa;
                b = ((low == upb) == (b < pb)) ? b : pb;
            }
        }
    }

    unsigned long long* wo = ws + (long)bid * CHUNK;
    wo[t]       = a;
    wo[t + 512] = b;
}

// ---------------------------------------------------------------------------
// Kernel B (fused): 64 blocks x 512 threads.
//  1. load 8 sorted runs -> LDS, merge-path merge in 3 stages (512 threads)
//  2. greedy in wave 0: 128 windows x 64 cand (1/lane), pays read from LDS;
//     O(1) sparse-table crossing filter SOFTWARE-PIPELINED one window ahead
//     (TT reads for w+1 issued before w's pop loop; accepts during w are
//     covered by a per-accept retest of the w+1 candidate);
//     62-lane LDS-atomic incremental table update per accept.
//  3. rank-sort of the <=128 selected by (start,end)
// ---------------------------------------------------------------------------
__global__ __launch_bounds__(TPB) void merge_greedy_kernel(
    const unsigned long long* __restrict__ ws,
    int* __restrict__ out)
{
    __shared__ __align__(16) unsigned long long keys[NCAND];  // 64 KiB
    // TT1[k][i] = max s2e over [i, i+2^k) ; TT2[k][i] = min e2s over [i, i+2^k)
    __shared__ int TT1[5][LMAX];              // 10 KiB
    __shared__ int TT2[5][LMAX];              // 10 KiB
    __shared__ unsigned acc_list[KOUT];
    __shared__ int      n_sh;
    __shared__ unsigned mkbuf[KOUT];
    __shared__ unsigned paybuf[KOUT];

    const int sent = blockIdx.x;
    const int tid  = threadIdx.x;
    const unsigned long long* wi = ws + (long)sent * NCAND;

    for (int i = tid; i < 5 * LMAX; i += TPB) {
        (&TT1[0][0])[i] = -1;
        (&TT2[0][0])[i] = LMAX;
    }
    {
        const ulonglong2* wi2 = (const ulonglong2*)wi;
        ulonglong2* k2 = (ulonglong2*)keys;
        for (int i = tid; i < NCAND / 2; i += TPB) k2[i] = wi2[i];
    }
    __syncthreads();

    // ---- merge: 8 sorted runs of 1024 -> 1 run of 8192 (3 stages) ----------
    #pragma unroll
    for (int stg = 0; stg < 3; ++stg) {
        const int Lh  = CHUNK << stg;          // 1024, 2048, 4096
        const int tpp = Lh >> 3;               // threads per pair
        const int pair = tid / tpp;
        const int o    = (tid % tpp) * 16;
        const unsigned long long* A = keys + pair * (Lh * 2);
        const unsigned long long* B = A + Lh;
        int lo = (o > Lh) ? o - Lh : 0;
        int hi = (o < Lh) ? o : Lh;
        while (lo < hi) {                      // smallest i : A[i] > B[o-1-i]
            int mid = (lo + hi) >> 1;
            if (A[mid] <= B[o - 1 - mid]) lo = mid + 1; else hi = mid;
        }
        int i = lo, j = o - lo;
        unsigned long long r[16];
        #pragma unroll
        for (int x = 0; x < 16; ++x) {
            bool ta = (j >= Lh) || (i < Lh && A[i] <= B[j]);
            r[x] = ta ? A[i++] : B[j++];
        }
        __syncthreads();                       // all reads done before overwrite
        unsigned long long* O = keys + pair * (Lh * 2) + o;
        #pragma unroll
        for (int x = 0; x < 16; ++x) O[x] = r[x];
        __syncthreads();
    }

    // ---- greedy: wave 0 only ------------------------------------------------
    if (tid < 64) {
        const int lane = tid;
        // incremental-update role: accepted (sst,sen) bumps TT1[k][i] for
        // i in [sst-2^k+1, sst] across 5 levels = 31 cells; TT2 likewise.
        const int sidel = (lane < 31) ? lane : (lane - 31);
        const int k_m   = 31 - __clz(sidel + 1);    // 0..4
        const int j_m   = sidel + 1 - (1 << k_m);   // 0..2^k-1
        int* const rowU = (lane < 31) ? &TT1[k_m][0] : &TT2[k_m][0];
        const unsigned* kw = (const unsigned*)keys; // low 32 bits = payload

        const int NW = NCAND / 64;                  // 128 windows
        unsigned payA = kw[(0 * 64 + lane) << 1];
        unsigned payB = kw[(1 * 64 + lane) << 1];
        int enA = (int)(payA & 511u), stA = (int)((payA >> 9) & 511u);
        int enB = (int)(payB & 511u), stB = (int)((payB >> 9) & 511u);

        // full filter for window 0 (TT currently empty)
        bool aliveA;
        {
            const int wd = enA - stA;
            bool cross = false;
            if (wd > 0) {
                if (wd < 32) {
                    const int k = 31 - __clz(wd), off = 1 << k;
                    const int mx = max(TT1[k][stA + 1], TT1[k][enA + 1 - off]);
                    const int mn = min(TT2[k][stA],     TT2[k][enA - off]);
                    cross = (mx > enA) || (mn < stA);
                } else {
                    for (int j = stA; j <= enA; ++j)
                        cross |= ((j > stA) && (TT1[0][j] > enA)) ||
                                 ((j < enA) && (TT2[0][j] < stA));
                }
            }
            aliveA = !cross;
        }
        bool aliveBacc = true;
        int n = 0;

        for (int w = 0; w < NW && n < KOUT; ++w) {
            // issue TT reads for NEXT window (state: accepts through w-1);
            // accepts during w are folded in via aliveBacc retests.
            const int wdB = enB - stB;
            int kB = (wdB >= 1) ? (31 - __clz(wdB)) : 0;
            if (kB > 4) kB = 4;
            const int offB = 1 << kB;
            int ia = stB + 1;        if (ia > 511) ia = 511;
            int ib = enB + 1 - offB; if (ib < 0)   ib = 0;
            const int ic = stB;
            int id = enB - offB;     if (id < 0)   id = 0;
            const int tA = TT1[kB][ia], tB = TT1[kB][ib];
            const int tC = TT2[kB][ic], tD = TT2[kB][id];

            // pop loop on current window (each pop IS an accept)
            for (;;) {
                const unsigned long long anyb = __ballot((int)aliveA);
                if (anyb == 0ull) break;
                const int lwin = __ffsll((long long)anyb) - 1;
                const unsigned spay = READLANE(payA, lwin);
                const int sen = (int)(spay & 511u);
                const int sst = (int)((spay >> 9) & 511u);

                if (lane == 62) acc_list[n] = spay;
                if (lane < 31)      { const int i = sst - j_m; if (i >= 0) atomicMax(&rowU[i], sen); }
                else if (lane < 62) { const int i = sen - j_m; if (i >= 0) atomicMin(&rowU[i], sst); }
                if (lane == lwin) aliveA = false;
                ++n;
                if (n >= KOUT) break;
                // retest my current candidate AND my next-window candidate
                const bool cA = ((stA < sst) & (sst <= enA) & (sen > enA)) |
                                ((sst < stA) & (sen >= stA) & (sen < enA));
                const bool cB = ((stB < sst) & (sst <= enB) & (sen > enB)) |
                                ((sst < stB) & (sen >= stB) & (sen < enB));
                aliveA    = aliveA    & !cA;
                aliveBacc = aliveBacc & !cB;
            }

            // combine next window's filter (TT part was read pre-pop)
            bool crossB;
            if (wdB >= 32) {                       // generic cold path (rare)
                crossB = false;
                for (int j = stB; j <= enB; ++j)
                    crossB |= ((j > stB) && (TT1[0][j] > enB)) ||
                              ((j < enB) && (TT2[0][j] < stB));
            } else {
                crossB = (wdB > 0) && ((max(tA, tB) > enB) || (min(tC, tD) < stB));
            }
            const bool aliveB = !crossB && aliveBacc;

            // shift pipeline: cur <- next, next <- w+2
            payA = payB; stA = stB; enA = enB; aliveA = aliveB;
            unsigned npay = 0u;
            if (w + 2 < NW) npay = kw[((w + 2) * 64 + lane) << 1];
            payB = npay;
            enB = (int)(payB & 511u); stB = (int)((payB >> 9) & 511u);
            aliveBacc = true;
        }
        if (lane == 0) n_sh = n;
    }
    __syncthreads();                            // publish acc_list / n_sh

    // ---- final (start,end) rank-sort + output (first 128 threads) ----------
    const int n = n_sh;
    if (tid < KOUT) {
        const unsigned p = (tid < n) ? acc_list[tid] : acc_list[0];
        paybuf[tid] = p;
        mkbuf[tid]  = ((p & 0x3FFFFu) << 7) | (unsigned)tid;   // stable tie-break
    }
    __syncthreads();
    if (tid < KOUT) {
        const unsigned mk = mkbuf[tid];
        int r = 0;
        #pragma unroll 8
        for (int t2 = 0; t2 < KOUT; ++t2) r += (mkbuf[t2] < mk) ? 1 : 0;
        out[sent * KOUT + r] = (int)(paybuf[tid] >> 18);
    }
}

// ---------------------------------------------------------------------------
// Fallback monolithic kernel (round-2, known-correct) if ws is too small.
// ---------------------------------------------------------------------------
__global__ __launch_bounds__(TPB) void extract_spans_mono(
    const float* __restrict__ scores,
    const int*   __restrict__ starts,
    const int*   __restrict__ ends,
    int*         __restrict__ out)
{
    __shared__ unsigned long long keys[NCAND];
    __shared__ unsigned acc_list[KOUT];
    __shared__ unsigned long long amask[TPB/64];
    __shared__ unsigned mkbuf[KOUT];
    __shared__ unsigned paybuf[KOUT];

    const int  sent = blockIdx.x;
    const int  tid  = threadIdx.x;
    const long base = (long)sent * NCAND;

    for (int i = tid; i < NCAND; i += TPB) {
        unsigned u = __float_as_uint(scores[base + i]);
        unsigned o = (u & 0x80000000u) ? ~u : (u | 0x80000000u);
        unsigned d = ~o;
        unsigned st = (unsigned)starts[base + i];
        unsigned en = (unsigned)ends[base + i];
        keys[i] = ((unsigned long long)d << 32) | ((unsigned)i << 18) | (st << 9) | en;
    }
    for (int k = 2; k <= NCAND; k <<= 1) {
        for (int j = k >> 1; j > 0; j >>= 1) {
            __syncthreads();
            for (int p = tid; p < NCAND / 2; p += TPB) {
                int low = p & (j - 1);
                int i   = ((p - low) << 1) | low;
                int q   = i | j;
                unsigned long long a = keys[i];
                unsigned long long b = keys[q];
                bool up = ((i & k) == 0);
                if ((a > b) == up) { keys[i] = b; keys[q] = a; }
            }
        }
    }
    __syncthreads();

    int  nn   = 0;
    bool done = false;
    for (int cb = 0; cb < NCAND && !done; cb += TPB) {
        const unsigned pay = (unsigned)keys[cb + tid];
        const int en = (int)(pay & 511u);
        const int st = (int)((pay >> 9) & 511u);
        bool alive = true;
        for (int a = 0; a < nn; ++a) {
            unsigned ap = acc_list[a];
            int ae = (int)(ap & 511u), as = (int)((ap >> 9) & 511u);
            if ((st < as && as <= en && ae > en) || (as < st && ae >= st && ae < en)) {
                alive = false; break;
            }
        }
        for (;;) {
            unsigned long long m = __ballot((int)alive);
            if ((tid & 63) == 0) amask[tid >> 6] = m;
            __syncthreads();
            int s = -1;
            #pragma unroll
            for (int w = 0; w < TPB / 64; ++w) {
                unsigned long long mw = amask[w];
                if (s < 0 && mw) s = (w << 6) + __ffsll((long long)mw) - 1;
            }
            __syncthreads();
            if (s < 0) break;
            unsigned spay = (unsigned)keys[cb + s];
            int sen = (int)(spay & 511u), sst = (int)((spay >> 9) & 511u);
            if (tid == 0) acc_list[nn] = spay;
            ++nn;
            if (nn == KOUT) { done = true; break; }
            if (alive) {
                alive = (tid != s) &&
                        !((st < sst && sst <= en && sen > en) ||
                          (sst < st && sen >= st && sen < en));
            }
        }
    }
    __syncthreads();
    if (tid < KOUT) {
        unsigned pay = (tid < nn) ? acc_list[tid] : acc_list[0];
        paybuf[tid] = pay;
        mkbuf[tid]  = ((pay & 0x3FFFFu) << 7) | (unsigned)tid;
    }
    __syncthreads();
    if (tid < KOUT) {
        unsigned mk = mkbuf[tid];
        int rank = 0;
        for (int t2 = 0; t2 < KOUT; ++t2)
            rank += (mkbuf[t2] < mk) ? 1 : 0;
        out[sent * KOUT + rank] = (int)(paybuf[tid] >> 18);
    }
}

extern "C" void kernel_launch(void* const* d_in, const int* in_sizes, int n_in,
                              void* d_out, int out_size, void* d_ws, size_t ws_size,
                              hipStream_t stream) {
    const float* scores = (const float*)d_in[0];
    const int*   starts = (const int*)d_in[1];
    const int*   ends   = (const int*)d_in[2];
    int*         out    = (int*)d_out;

    const size_t ws_needed = (size_t)NSENT * NCAND * sizeof(unsigned long long); // 4 MiB
    if (ws_size >= ws_needed) {
        unsigned long long* ws = (unsigned long long*)d_ws;
        sort_chunks_kernel<<<NSENT * NCHUNK, TPB, 0, stream>>>(scores, starts, ends, ws);
        merge_greedy_kernel<<<NSENT, TPB, 0, stream>>>(ws, out);
    } else {
        extract_spans_mono<<<NSENT, TPB, 0, stream>>>(scores, starts, ends, out);
    }
}

// Round 11
// 121.169 us; speedup vs baseline: 1.0757x; 1.0757x over previous
//
#include <hip/hip_runtime.h>

#define NSENT 64
#define NCAND 8192
#define LMAX  512
#define KOUT  128
#define TPB   512
#define CHUNK 1024
#define NCHUNK (NCAND / CHUNK)   // 8
#define P1    1024               // serial-greedy prefix
#define NCH2  ((NCAND - P1) / TPB)  // 14 pass-2 chunks
#define SURV_CAP 2048

#if defined(__has_builtin)
#if __has_builtin(__builtin_amdgcn_readlane)
#define READLANE(v, l) __builtin_amdgcn_readlane((unsigned)(v), (unsigned)(l))
#endif
#endif
#ifndef READLANE
#define READLANE(v, l) ((unsigned)__shfl((int)(v), (int)(l)))
#endif

// ---------------------------------------------------------------------------
// Kernel A (reverted to R7 form): 512 blocks (sentence = bid>>3, chunk = bid&7).
// Bitonic-sort 1024 u64 keys in LDS, write sorted chunk to ws.
// Key: high 32 = descending-orderable score bits, low 31 = (idx<<18)|(st<<9)|en
// ---------------------------------------------------------------------------
__global__ __launch_bounds__(TPB) void sort_chunks_kernel(
    const float* __restrict__ scores,
    const int*   __restrict__ starts,
    const int*   __restrict__ ends,
    unsigned long long* __restrict__ ws)
{
    __shared__ unsigned long long lk[CHUNK];
    const int  bid   = blockIdx.x;
    const int  sent  = bid >> 3;
    const int  chunk = bid & 7;
    const int  tid   = threadIdx.x;
    const long gbase = (long)sent * NCAND + (long)chunk * CHUNK;

    for (int i = tid; i < CHUNK; i += TPB) {
        unsigned u  = __float_as_uint(scores[gbase + i]);
        unsigned o  = (u & 0x80000000u) ? ~u : (u | 0x80000000u); // asc-orderable
        unsigned d  = ~o;                                          // descending
        unsigned st = (unsigned)starts[gbase + i];
        unsigned en = (unsigned)ends[gbase + i];
        unsigned gi = (unsigned)(chunk * CHUNK + i);               // idx in sentence
        lk[i] = ((unsigned long long)d << 32) | (gi << 18) | (st << 9) | en;
    }

    for (int k = 2; k <= CHUNK; k <<= 1) {
        for (int j = k >> 1; j > 0; j >>= 1) {
            __syncthreads();
            const int p   = tid;               // CHUNK/2 == TPB: one CX per thread
            const int low = p & (j - 1);
            const int i   = ((p - low) << 1) | low;
            const int q   = i | j;
            unsigned long long a = lk[i];
            unsigned long long b = lk[q];
            bool up = ((i & k) == 0);
            if ((a > b) == up) { lk[i] = b; lk[q] = a; }
        }
    }
    __syncthreads();

    unsigned long long* wo = ws + (long)bid * CHUNK;
    for (int i = tid; i < CHUNK; i += TPB) wo[i] = lk[i];
}

// crossing test vs sparse range-max/min tables:
// crossing iff max s2e[st+1..en] > en  or  min e2s[st..en-1] < st
__device__ __forceinline__ bool tt_cross(int st, int en,
    const int (*T1)[LMAX], const int (*T2)[LMAX])
{
    const int wd = en - st;
    if (wd <= 0) return false;
    if (wd < 32) {
        const int k   = 31 - __clz(wd);
        const int off = 1 << k;
        const int mx  = max(T1[k][st + 1], T1[k][en + 1 - off]);
        const int mn  = min(T2[k][st],     T2[k][en - off]);
        return (mx > en) || (mn < st);
    }
    bool cross = false;
    for (int j = st; j <= en; ++j)
        cross |= ((j > st) && (T1[0][j] > en)) || ((j < en) && (T2[0][j] < st));
    return cross;
}

// serial pop loop over one 64-candidate window (validated r8-r10 structure);
// mutates: alive, n. uses: pay, st, en, lane, j_m, rowU, acc_list.
#define POP_WINDOW_LOOP()                                                      \
    for (;;) {                                                                 \
        const unsigned long long anyb = __ballot((int)alive);                  \
        if (anyb == 0ull) break;                                               \
        const int lwin = __ffsll((long long)anyb) - 1;                         \
        const unsigned spay = READLANE(pay, lwin);                             \
        const int sen = (int)(spay & 511u);                                    \
        const int sst = (int)((spay >> 9) & 511u);                             \
        if (lane == 62) acc_list[n] = spay;                                    \
        if (lane < 31)      { const int ii = sst - j_m; if (ii >= 0) atomicMax(&rowU[ii], sen); } \
        else if (lane < 62) { const int ii = sen - j_m; if (ii >= 0) atomicMin(&rowU[ii], sst); } \
        if (lane == lwin) alive = false;                                       \
        ++n;                                                                   \
        if (n >= KOUT) break;                                                  \
        const bool cR = ((st < sst) & (sst <= en) & (sen > en)) |              \
                        ((sst < st) & (sen >= st) & (sen < en));               \
        alive = alive & !cR;                                                   \
    }

// ---------------------------------------------------------------------------
// Kernel B: 64 blocks x 512 threads.
//  1. load 8 sorted runs -> LDS, merge-path merge (3 stages, 512 threads)
//  2. greedy, 3 phases:
//     P1: wave 0, windows over first P1=1024 candidates (validated loop)
//     P2: ALL threads stale-filter remaining 7168 vs TT snapshot (kills are
//         monotone => final), stable-compact survivors (~130) into surv[]
//     P3: wave 0, windows over surv[] (fresh TT filter + per-pop retest);
//         overflow tail loop from first unstored candidate (normally never)
//  3. parallel rank-sort of the <=128 selected by (start,end)
// ---------------------------------------------------------------------------
__global__ __launch_bounds__(TPB) void merge_greedy_kernel(
    const unsigned long long* __restrict__ ws,
    int* __restrict__ out)
{
    __shared__ __align__(16) unsigned long long keys[NCAND];  // 64 KiB
    __shared__ int TT1[5][LMAX];              // 10 KiB
    __shared__ int TT2[5][LMAX];              // 10 KiB
    __shared__ unsigned surv[SURV_CAP];       // 8 KiB (payloads, sorted order)
    __shared__ unsigned long long pmask[NCH2][8];
    __shared__ unsigned acc_list[KOUT];
    __shared__ int n_sh, nsurv_sh, tail_sh;
    __shared__ unsigned mkbuf[KOUT];
    __shared__ unsigned paybuf[KOUT];

    const int sent = blockIdx.x;
    const int tid  = threadIdx.x;
    const unsigned long long* wi = ws + (long)sent * NCAND;

    for (int i = tid; i < 5 * LMAX; i += TPB) {
        (&TT1[0][0])[i] = -1;
        (&TT2[0][0])[i] = LMAX;
    }
    if (tid == 0) { n_sh = 0; nsurv_sh = 0; tail_sh = NCAND; }
    {
        const ulonglong2* wi2 = (const ulonglong2*)wi;
        ulonglong2* k2 = (ulonglong2*)keys;
        for (int i = tid; i < NCAND / 2; i += TPB) k2[i] = wi2[i];
    }
    __syncthreads();

    // ---- merge: 8 sorted runs of 1024 -> 1 run of 8192 (3 stages) ----------
    #pragma unroll
    for (int stg = 0; stg < 3; ++stg) {
        const int Lh  = CHUNK << stg;          // 1024, 2048, 4096
        const int tpp = Lh >> 3;               // threads per pair
        const int pair = tid / tpp;
        const int o    = (tid % tpp) * 16;
        const unsigned long long* A = keys + pair * (Lh * 2);
        const unsigned long long* B = A + Lh;
        int lo = (o > Lh) ? o - Lh : 0;
        int hi = (o < Lh) ? o : Lh;
        while (lo < hi) {                      // smallest i : A[i] > B[o-1-i]
            int mid = (lo + hi) >> 1;
            if (A[mid] <= B[o - 1 - mid]) lo = mid + 1; else hi = mid;
        }
        int i = lo, j = o - lo;
        unsigned long long r[16];
        #pragma unroll
        for (int x = 0; x < 16; ++x) {
            bool ta = (j >= Lh) || (i < Lh && A[i] <= B[j]);
            r[x] = ta ? A[i++] : B[j++];
        }
        __syncthreads();                       // all reads done before overwrite
        unsigned long long* O = keys + pair * (Lh * 2) + o;
        #pragma unroll
        for (int x = 0; x < 16; ++x) O[x] = r[x];
        __syncthreads();
    }

    const unsigned* kw = (const unsigned*)keys;     // low word = payload

    // ---- P1: wave 0, serial windows over keys[0..P1) ------------------------
    if (tid < 64) {
        const int lane = tid;
        const int sidel = (lane < 31) ? lane : (lane - 31);
        const int k_m   = 31 - __clz(sidel + 1);
        const int j_m   = sidel + 1 - (1 << k_m);
        int* const rowU = (lane < 31) ? &TT1[k_m][0] : &TT2[k_m][0];

        int n = 0;
        for (int w = 0; w < P1 / 64 && n < KOUT; ++w) {
            const unsigned pay = kw[(w * 64 + lane) << 1];
            const int en = (int)(pay & 511u);
            const int st = (int)((pay >> 9) & 511u);
            bool alive = !tt_cross(st, en, TT1, TT2);
            POP_WINDOW_LOOP();
        }
        if (lane == 0) n_sh = n;
    }
    __syncthreads();                            // TT + n_sh visible

    // ---- P2: all threads, stale filter + stable compaction ------------------
    const int n1 = n_sh;
    unsigned mypay[NCH2];
    bool     myalive[NCH2];
    if (n1 < KOUT) {
        #pragma unroll
        for (int c = 0; c < NCH2; ++c) {
            const int i = P1 + c * TPB + tid;
            const unsigned pay = kw[i << 1];
            const int en = (int)(pay & 511u);
            const int st = (int)((pay >> 9) & 511u);
            const bool alive = !tt_cross(st, en, TT1, TT2);
            mypay[c] = pay; myalive[c] = alive;
            const unsigned long long b = __ballot((int)alive);
            if ((tid & 63) == 0) pmask[c][tid >> 6] = b;
        }
    }
    __syncthreads();
    if (n1 < KOUT) {
        const int myw = tid >> 6;
        const unsigned long long below = (1ull << (tid & 63)) - 1ull;
        unsigned run = 0;
        #pragma unroll
        for (int c = 0; c < NCH2; ++c) {
            unsigned off = 0;
            #pragma unroll
            for (int w = 0; w < 8; ++w) {
                const unsigned long long m = pmask[c][w];
                if (w == myw) off = run + (unsigned)__popcll(m & below);
                run += (unsigned)__popcll(m);
            }
            if (myalive[c]) {
                if (off < SURV_CAP) surv[off] = mypay[c];
                else atomicMin(&tail_sh, P1 + c * TPB + tid);  // first unstored
            }
        }
        if (tid == 0) nsurv_sh = (run < SURV_CAP) ? (int)run : SURV_CAP;
    }
    __syncthreads();

    // ---- P3: wave 0, windows over surv[], then (rare) tail ------------------
    if (tid < 64) {
        const int lane = tid;
        const int sidel = (lane < 31) ? lane : (lane - 31);
        const int k_m   = 31 - __clz(sidel + 1);
        const int j_m   = sidel + 1 - (1 << k_m);
        int* const rowU = (lane < 31) ? &TT1[k_m][0] : &TT2[k_m][0];

        int n = n_sh;
        const int nsurv = nsurv_sh;
        for (int s = 0; s < nsurv && n < KOUT; s += 64) {
            const int i = s + lane;
            const bool have = i < nsurv;
            const unsigned pay = surv[have ? i : 0];
            const int en = (int)(pay & 511u);
            const int st = (int)((pay >> 9) & 511u);
            bool alive = have && !tt_cross(st, en, TT1, TT2);
            POP_WINDOW_LOOP();
        }
        // overflow tail: re-scan candidates from tail_sh (monotone kills make
        // re-filtering the dead ones harmless). Normally tail_sh == NCAND.
        for (int cb = tail_sh; cb < NCAND && n < KOUT; cb += 64) {
            const int i = cb + lane;
            const bool have = i < NCAND;
            const unsigned pay = kw[(have ? i : 0) << 1];
            const int en = (int)(pay & 511u);
            const int st = (int)((pay >> 9) & 511u);
            bool alive = have && !tt_cross(st, en, TT1, TT2);
            POP_WINDOW_LOOP();
        }
        if (lane == 0) n_sh = n;
    }
    __syncthreads();                            // publish acc_list / n_sh

    // ---- final (start,end) rank-sort + output (first 128 threads) ----------
    const int n = n_sh;
    if (tid < KOUT) {
        const unsigned p = (tid < n) ? acc_list[tid] : acc_list[0];
        paybuf[tid] = p;
        mkbuf[tid]  = ((p & 0x3FFFFu) << 7) | (unsigned)tid;   // stable tie-break
    }
    __syncthreads();
    if (tid < KOUT) {
        const unsigned mk = mkbuf[tid];
        int r = 0;
        #pragma unroll 8
        for (int t2 = 0; t2 < KOUT; ++t2) r += (mkbuf[t2] < mk) ? 1 : 0;
        out[sent * KOUT + r] = (int)(paybuf[tid] >> 18);
    }
}

// ---------------------------------------------------------------------------
// Fallback monolithic kernel (round-2, known-correct) if ws is too small.
// ---------------------------------------------------------------------------
__global__ __launch_bounds__(TPB) void extract_spans_mono(
    const float* __restrict__ scores,
    const int*   __restrict__ starts,
    const int*   __restrict__ ends,
    int*         __restrict__ out)
{
    __shared__ unsigned long long keys[NCAND];
    __shared__ unsigned acc_list[KOUT];
    __shared__ unsigned long long amask[TPB/64];
    __shared__ unsigned mkbuf[KOUT];
    __shared__ unsigned paybuf[KOUT];

    const int  sent = blockIdx.x;
    const int  tid  = threadIdx.x;
    const long base = (long)sent * NCAND;

    for (int i = tid; i < NCAND; i += TPB) {
        unsigned u = __float_as_uint(scores[base + i]);
        unsigned o = (u & 0x80000000u) ? ~u : (u | 0x80000000u);
        unsigned d = ~o;
        unsigned st = (unsigned)starts[base + i];
        unsigned en = (unsigned)ends[base + i];
        keys[i] = ((unsigned long long)d << 32) | ((unsigned)i << 18) | (st << 9) | en;
    }
    for (int k = 2; k <= NCAND; k <<= 1) {
        for (int j = k >> 1; j > 0; j >>= 1) {
            __syncthreads();
            for (int p = tid; p < NCAND / 2; p += TPB) {
                int low = p & (j - 1);
                int i   = ((p - low) << 1) | low;
                int q   = i | j;
                unsigned long long a = keys[i];
                unsigned long long b = keys[q];
                bool up = ((i & k) == 0);
                if ((a > b) == up) { keys[i] = b; keys[q] = a; }
            }
        }
    }
    __syncthreads();

    int  nn   = 0;
    bool done = false;
    for (int cb = 0; cb < NCAND && !done; cb += TPB) {
        const unsigned pay = (unsigned)keys[cb + tid];
        const int en = (int)(pay & 511u);
        const int st = (int)((pay >> 9) & 511u);
        bool alive = true;
        for (int a = 0; a < nn; ++a) {
            unsigned ap = acc_list[a];
            int ae = (int)(ap & 511u), as = (int)((ap >> 9) & 511u);
            if ((st < as && as <= en && ae > en) || (as < st && ae >= st && ae < en)) {
                alive = false; break;
            }
        }
        for (;;) {
            unsigned long long m = __ballot((int)alive);
            if ((tid & 63) == 0) amask[tid >> 6] = m;
            __syncthreads();
            int s = -1;
            #pragma unroll
            for (int w = 0; w < TPB / 64; ++w) {
                unsigned long long mw = amask[w];
                if (s < 0 && mw) s = (w << 6) + __ffsll((long long)mw) - 1;
            }
            __syncthreads();
            if (s < 0) break;
            unsigned spay = (unsigned)keys[cb + s];
            int sen = (int)(spay & 511u), sst = (int)((spay >> 9) & 511u);
            if (tid == 0) acc_list[nn] = spay;
            ++nn;
            if (nn == KOUT) { done = true; break; }
            if (alive) {
                alive = (tid != s) &&
                        !((st < sst && sst <= en && sen > en) ||
                          (sst < st && sen >= st && sen < en));
            }
        }
    }
    __syncthreads();
    if (tid < KOUT) {
        unsigned pay = (tid < nn) ? acc_list[tid] : acc_list[0];
        paybuf[tid] = pay;
        mkbuf[tid]  = ((pay & 0x3FFFFu) << 7) | (unsigned)tid;
    }
    __syncthreads();
    if (tid < KOUT) {
        unsigned mk = mkbuf[tid];
        int rank = 0;
        for (int t2 = 0; t2 < KOUT; ++t2)
            rank += (mkbuf[t2] < mk) ? 1 : 0;
        out[sent * KOUT + rank] = (int)(paybuf[tid] >> 18);
    }
}

extern "C" void kernel_launch(void* const* d_in, const int* in_sizes, int n_in,
                              void* d_out, int out_size, void* d_ws, size_t ws_size,
                              hipStream_t stream) {
    const float* scores = (const float*)d_in[0];
    const int*   starts = (const int*)d_in[1];
    const int*   ends   = (const int*)d_in[2];
    int*         out    = (int*)d_out;

    const size_t ws_needed = (size_t)NSENT * NCAND * sizeof(unsigned long long); // 4 MiB
    if (ws_size >= ws_needed) {
        unsigned long long* ws = (unsigned long long*)d_ws;
        sort_chunks_kernel<<<NSENT * NCHUNK, TPB, 0, stream>>>(scores, starts, ends, ws);
        merge_greedy_kernel<<<NSENT, TPB, 0, stream>>>(ws, out);
    } else {
        extract_spans_mono<<<NSENT, TPB, 0, stream>>>(scores, starts, ends, out);
    }
}